// Round 3
// baseline (616.865 us; speedup 1.0000x reference)
//
#include <hip/hip_runtime.h>
#include <cstdint>
#include <cstddef>

// PointerNetwork: B=256, S=512, H=128, CHAR/CLASS=10, OUT=64, WE=32
// R2 design:
//  - k_lstm: 256 thr/block, __launch_bounds__(256,1) -> 512-reg unified budget.
//    4 k-slices (q=T&3), 64 col-groups x 8 cols (g=T>>2). Weights fp16 in
//    96 uint4 = 384 regs/thread (VGPR+AGPR). DPP quad_perm bfly over q.
//  - bank-conflict fixes: rotated slice loads, padded zsum (p(c)=c+4*(c>>3)).
//  - 3 kernels total: k_prep (XW1 + fp16 pack), k_lstm, k_out (subject GEMV
//    + per-slot LN/po/sub folded, then scatter).

#define SLOTS 192

typedef _Float16 f16x2 __attribute__((ext_vector_type(2)));

__device__ __forceinline__ f16x2 as_h2(unsigned int v) {
    union { unsigned int u; f16x2 h; } x; x.u = v; return x.h;
}

#if __has_builtin(__builtin_amdgcn_fdot2)
__device__ __forceinline__ float fdot2(f16x2 a, f16x2 b, float c) {
    return __builtin_amdgcn_fdot2(a, b, c, false);
}
#else
__device__ __forceinline__ float fdot2(f16x2 a, f16x2 b, float c) {
    return c + (float)a.x * (float)b.x + (float)a.y * (float)b.y;
}
#endif

__device__ __forceinline__ float fast_rcp(float x) {
#if __has_builtin(__builtin_amdgcn_rcpf)
    return __builtin_amdgcn_rcpf(x);
#else
    return 1.f / x;
#endif
}
__device__ __forceinline__ float sigm(float x) {
    x = fminf(fmaxf(x, -30.f), 30.f);
    return fast_rcp(1.f + __expf(-x));
}
__device__ __forceinline__ float tanh_fast(float x) {
    x = fminf(fmaxf(x, -15.f), 15.f);
    float e = __expf(-2.f * x);
    return (1.f - e) * fast_rcp(1.f + e);
}

// butterfly add over lane quads (q = lane&3) via DPP quad_perm, VALU-only.
__device__ __forceinline__ float bfly4(float v) {
    union { float f; int i; } a, b;
    a.f = v;
    b.i = __builtin_amdgcn_update_dpp(0, a.i, 0xB1, 0xf, 0xf, true);   // [1,0,3,2] xor1
    a.f += b.f;
    b.i = __builtin_amdgcn_update_dpp(0, a.i, 0x4E, 0xf, 0xf, true);   // [2,3,0,1] xor2
    a.f += b.f;
    return a.f;
}

// zsum padded index: +4 floats per 8 cols (breaks the 128B stride conflict)
__device__ __forceinline__ int zp(int c) { return c + 4 * (c >> 3); }

// ---------------- P: XW1 table (blocks 0-9) + fp16 pack (blocks 10-105) -----
// W1P[T*32 + j*4 + u]: lstm-thread T=(q=T&3,g=T>>2), col=8g+j, k=32q+8u+2e+{0,1}
// W2P[T*64 + j*8 + u]: k2=64q+8u+2e; k2<128 -> l2_Wx row k2, else l2_Wh row k2-128
__global__ void k_prep(const float* __restrict__ emb_char,
                       const float* __restrict__ emb_word,
                       const float* __restrict__ Wwc,
                       const float* __restrict__ bwc,
                       const float* __restrict__ l1_Wx,
                       const float* __restrict__ l1_b,
                       const float* __restrict__ l1_Wh,
                       const float* __restrict__ l2_Wx,
                       const float* __restrict__ l2_Wh,
                       float* __restrict__ XW1,
                       uint4* __restrict__ W1P, uint4* __restrict__ W2P) {
    const int T = threadIdx.x;   // 0..255
    if (blockIdx.x < 10) {
        __shared__ float xt[64];
        const int w = blockIdx.x;
        if (T < 64) {
            float acc = emb_char[T] + bwc[T];   // emb_char row 0 (char_id==0)
            for (int m = 0; m < 32; ++m) acc += emb_word[w * 32 + m] * Wwc[m * 64 + T];
            xt[T] = acc;
        }
        __syncthreads();
        for (int col = T; col < 512; col += 256) {
            float acc = l1_b[col];
            for (int k = 0; k < 64; ++k) acc += xt[k] * l1_Wx[k * 512 + col];
            XW1[w * 512 + col] = acc;
        }
        return;
    }
    const int gid = (blockIdx.x - 10) * 256 + T;   // 0..24575
    union { uint4 qv; f16x2 h[4]; } out;
    if (gid < 8192) {
        const int t = gid >> 5, idx = gid & 31;
        const int q = t & 3, g = t >> 2;
        const int j = idx >> 2, u = idx & 3;
        const int col = 8 * g + j;
        for (int e = 0; e < 4; ++e) {
            const int k = 32 * q + 8 * u + 2 * e;
            f16x2 p;
            p.x = (_Float16)l1_Wh[k * 512 + col];
            p.y = (_Float16)l1_Wh[(k + 1) * 512 + col];
            out.h[e] = p;
        }
        W1P[gid] = out.qv;
    } else {
        const int gid2 = gid - 8192;               // 0..16383
        const int t = gid2 >> 6, idx = gid2 & 63;
        const int q = t & 3, g = t >> 2;
        const int j = idx >> 3, u = idx & 7;
        const int col = 8 * g + j;
        for (int e = 0; e < 4; ++e) {
            const int k2 = 64 * q + 8 * u + 2 * e;   // 0..254 even
            float w0, w1v;
            if (k2 < 128) { w0 = l2_Wx[k2 * 512 + col];         w1v = l2_Wx[(k2 + 1) * 512 + col]; }
            else          { w0 = l2_Wh[(k2 - 128) * 512 + col]; w1v = l2_Wh[(k2 - 127) * 512 + col]; }
            f16x2 p; p.x = (_Float16)w0; p.y = (_Float16)w1v;
            out.h[e] = p;
        }
        W2P[gid2] = out.qv;
    }
}

// ---------------- main recurrent kernel: 1 block (256 thr) per batch row ----
__global__ __launch_bounds__(256, 1) void k_lstm(
    const int* __restrict__ char_ids, const int* __restrict__ word_ids,
    const float* __restrict__ XW1, const uint4* __restrict__ W1P,
    const uint4* __restrict__ W2P, const float* __restrict__ l2_b,
    float* __restrict__ hbuf, unsigned short* __restrict__ idxbuf)
{
    const int b    = blockIdx.x;
    const int T    = threadIdx.x;   // 0..255
    const int lane = T & 63;
    const int wv   = T >> 6;        // 0..3
    const int q    = T & 3;         // k-slice
    const int g    = T >> 2;        // column group: cols 8g..8g+7

    __shared__ int charL[512];
    __shared__ int wordL[512];
    __shared__ __align__(16)  float zs1[768];   // padded, zp(c)=c+4*(c>>3)
    __shared__ __align__(16)  float zs2[768];
    __shared__ __align__(128) uint4 h1q[16];    // 128 fp16 h1
    __shared__ __align__(128) uint4 h2q[16];
    __shared__ short actT[512];
    __shared__ int   ccnt[8];

    charL[T] = char_ids[b * 512 + T];
    charL[256 + T] = char_ids[b * 512 + 256 + T];
    wordL[T] = word_ids[b * 512 + T];
    wordL[256 + T] = word_ids[b * 512 + 256 + T];
    __syncthreads();

    // compact the active-step list (ordered) + write idx map (2 positions/thr)
    const bool a0 = (charL[T] == 0);
    const bool a1 = (charL[256 + T] == 0);
    const unsigned long long m0 = __ballot(a0);
    const unsigned long long m1 = __ballot(a1);
    if (lane == 0) { ccnt[wv] = (int)__popcll(m0); ccnt[4 + wv] = (int)__popcll(m1); }
    __syncthreads();
    int base0 = 0, base4 = 0, tot = 0;
    for (int i = 0; i < 8; ++i) {
        const int c = ccnt[i];
        if (i < wv) base0 += c;
        if (i < 4 + wv) base4 += c;
        tot += c;
    }
    const unsigned long long below = (1ull << lane) - 1ull;
    const unsigned long long upto  = (2ull << lane) - 1ull;
    if (a0) actT[base0 + (int)__popcll(m0 & below)] = (short)T;
    if (a1) actT[base4 + (int)__popcll(m1 & below)] = (short)(256 + T);
    {
        int c0 = base0 + (int)__popcll(m0 & upto);
        int c1i = base4 + (int)__popcll(m1 & upto);
        idxbuf[b * 512 + T] = (unsigned short)(c0 < SLOTS - 1 ? c0 : SLOTS - 1);
        idxbuf[b * 512 + 256 + T] = (unsigned short)(c1i < SLOTS - 1 ? c1i : SLOTS - 1);
    }
    const int nact = tot;

    // init state
    if (T < 32) { (T < 16 ? h1q : h2q)[T & 15] = make_uint4(0, 0, 0, 0); }
    if (T < 128) hbuf[(size_t)b * SLOTS * 128 + T] = 0.f;   // slot 0 = zeros
    float c1 = 0.f, c2 = 0.f;
    float l2b0 = 0.f, l2b1 = 0.f, l2b2 = 0.f, l2b3 = 0.f;
    if (T < 128) {
        l2b0 = l2_b[T]; l2b1 = l2_b[128 + T]; l2b2 = l2_b[256 + T]; l2b3 = l2_b[384 + T];
    }

    // persistent fp16 weight slices: 96 uint4 = 384 regs/thread (v+a unified)
    uint4 w1[32], w2[64];
    {
        const uint4* W1t = W1P + (size_t)T * 32;
        const uint4* W2t = W2P + (size_t)T * 64;
#pragma unroll
        for (int i = 0; i < 32; ++i) w1[i] = W1t[i];
#pragma unroll
        for (int i = 0; i < 64; ++i) w2[i] = W2t[i];
    }
    __syncthreads();

    for (int a = 0; a < nact; ++a) {
        const int t = actT[a];          // LDS broadcast
        const int w = wordL[t];
        // gate threads prefetch XW1 entries (latency hidden behind phase A)
        float xwi = 0.f, xwf = 0.f, xwg = 0.f, xwo = 0.f;
        if (T < 128) {
            const float* xr = XW1 + w * 512 + T;
            xwi = xr[0]; xwf = xr[128]; xwg = xr[256]; xwo = xr[384];
        }

        // ---- phase A: layer-1 partial dots on k-slice q, cols 8g..8g+7 ----
        {
            uint4 hA[4];
#pragma unroll
            for (int rr = 0; rr < 4; ++rr) {   // rotated order: bank spread
                const int u = (rr + q) & 3;
                hA[u] = h1q[4 * q + u];
            }
            float acc[8];
#pragma unroll
            for (int j = 0; j < 8; ++j) {
                float s = 0.f;
#pragma unroll
                for (int u = 0; u < 4; ++u) {
                    const uint4 wq = w1[j * 4 + u];
                    const uint4 hq = hA[u];
                    s = fdot2(as_h2(hq.x), as_h2(wq.x), s);
                    s = fdot2(as_h2(hq.y), as_h2(wq.y), s);
                    s = fdot2(as_h2(hq.z), as_h2(wq.z), s);
                    s = fdot2(as_h2(hq.w), as_h2(wq.w), s);
                }
                acc[j] = bfly4(s);
            }
            if (q == 0) {
                const int pb = 12 * g;   // zp(8g)
#pragma unroll
                for (int m = 0; m < 4; ++m) {
                    float2 v; v.x = acc[2 * m]; v.y = acc[2 * m + 1];
                    *(float2*)&zs1[pb + 2 * m] = v;
                }
            }
        }
        __syncthreads();

        // ---- phase B: layer-1 gates (unit u = T) ----
        if (T < 128) {
            const float zi = zs1[zp(T)]       + xwi;
            const float zf = zs1[zp(128 + T)] + xwf;
            const float zg = zs1[zp(256 + T)] + xwg;
            const float zo = zs1[zp(384 + T)] + xwo;
            c1 = sigm(zf) * c1 + sigm(zi) * tanh_fast(zg);
            ((_Float16*)h1q)[T] = (_Float16)(sigm(zo) * tanh_fast(c1));
        }
        __syncthreads();

        // ---- phase C: layer-2 partial dots (K=256 concat [h1n; h2]) ----
        {
            const uint4* hbase = (q < 2) ? (h1q + 8 * (q & 1)) : (h2q + 8 * (q & 1));
            uint4 hC[8];
#pragma unroll
            for (int rr = 0; rr < 8; ++rr) {   // rotated order: bank spread
                const int u = (rr + 2 * q) & 7;
                hC[u] = hbase[u];
            }
            float acc[8];
#pragma unroll
            for (int j = 0; j < 8; ++j) {
                float s = 0.f;
#pragma unroll
                for (int u = 0; u < 8; ++u) {
                    const uint4 wq = w2[j * 8 + u];
                    const uint4 hq = hC[u];
                    s = fdot2(as_h2(hq.x), as_h2(wq.x), s);
                    s = fdot2(as_h2(hq.y), as_h2(wq.y), s);
                    s = fdot2(as_h2(hq.z), as_h2(wq.z), s);
                    s = fdot2(as_h2(hq.w), as_h2(wq.w), s);
                }
                acc[j] = bfly4(s);
            }
            if (q == 0) {
                const int pb = 12 * g;
#pragma unroll
                for (int m = 0; m < 4; ++m) {
                    float2 v; v.x = acc[2 * m]; v.y = acc[2 * m + 1];
                    *(float2*)&zs2[pb + 2 * m] = v;
                }
            }
        }
        __syncthreads();

        // ---- phase D: layer-2 gates + hbuf write ----
        if (T < 128) {
            const float zi = zs2[zp(T)]       + l2b0;
            const float zf = zs2[zp(128 + T)] + l2b1;
            const float zg = zs2[zp(256 + T)] + l2b2;
            const float zo = zs2[zp(384 + T)] + l2b3;
            c2 = sigm(zf) * c2 + sigm(zi) * tanh_fast(zg);
            const float h2n = sigm(zo) * tanh_fast(c2);
            ((_Float16*)h2q)[T] = (_Float16)h2n;
            const int slot = (a + 1 < SLOTS - 1) ? a + 1 : SLOTS - 1;
            hbuf[((size_t)b * SLOTS + slot) * 128 + T] = h2n;
        }
        __syncthreads();
    }
}

// ---------------- OUT: subject GEMV + per-slot LN/po/sub + scatter ----------
// po(s,o) = rs*sum_c(gm[c]*pw[c][o]*h[s][c]) - u*rs*K2[o] + K1[o]
//   K1[o] = po_b[o] + sum_c bt[c]*pw[c][o];  K2[o] = sum_c gm[c]*pw[c][o]
__global__ __launch_bounds__(256) void k_out(
    const int* __restrict__ subject_ids,
    const unsigned short* __restrict__ idxbuf, const float* __restrict__ hbuf,
    const float* __restrict__ beta_W, const float* __restrict__ beta_b,
    const float* __restrict__ gamma_W, const float* __restrict__ gamma_b,
    const float* __restrict__ sub_W, const float* __restrict__ sub_b,
    const float* __restrict__ po_W, const float* __restrict__ po_b,
    float* __restrict__ out)
{
    const int b = blockIdx.x;
    const int T = threadIdx.x;   // 0..255
    __shared__ float A[20][132];          // A[o][c] = gm[c]*po_W[c*20+o]
    __shared__ float K1[20], K2[20];
    __shared__ float gm[128], bt[128];
    __shared__ float subj[256];
    __shared__ float urs[SLOTS][2];
    __shared__ float povals[SLOTS * 20];
    __shared__ float subv[SLOTS * 2];
    __shared__ unsigned short idxr[512];
    __shared__ float swl[256];

    idxr[T] = idxbuf[b * 512 + T];
    idxr[256 + T] = idxbuf[b * 512 + 256 + T];
    swl[T] = sub_W[T];
    {
        const int s0 = subject_ids[b * 2 + 0];
        const int s1 = subject_ids[b * 2 + 1];
        const int i0 = idxbuf[b * 512 + s0];
        const int i1 = idxbuf[b * 512 + s1];
        if (T < 128) subj[T] = hbuf[((size_t)b * SLOTS + i0) * 128 + T];
        else         subj[T] = hbuf[((size_t)b * SLOTS + i1) * 128 + (T - 128)];
    }
    __syncthreads();

    // beta (T<128) / gamma (T>=128) GEMV
    {
        const int u = T & 127;
        const float* Wm = (T < 128) ? beta_W : gamma_W;
        float acc = (T < 128) ? beta_b[u] : gamma_b[u];
        for (int c = 0; c < 256; ++c) acc += subj[c] * Wm[c * 128 + u];
        if (T < 128) bt[u] = acc; else gm[u] = acc;
    }
    __syncthreads();

    // A fill + K1/K2 + per-slot stats & sub head
    for (int i = T; i < 2560; i += 256) {
        const int o = i >> 7, c = i & 127;
        A[o][c] = gm[c] * po_W[c * 20 + o];
    }
    if (T < 20) {
        float k1 = po_b[T], k2 = 0.f;
        for (int c = 0; c < 128; ++c) {
            const float pw = po_W[c * 20 + T];
            k1 += bt[c] * pw;
            k2 += gm[c] * pw;
        }
        K1[T] = k1; K2[T] = k2;
    }
    const int nslot = (int)idxr[511] + 1;
    const float sb0 = sub_b[0], sb1 = sub_b[1];
    for (int s = T; s < nslot; s += 256) {
        const float4* hp4 = (const float4*)(hbuf + ((size_t)b * SLOTS + s) * 128);
        float sum = 0.f, s2 = 0.f, sub0 = sb0, sub1 = sb1;
        for (int c4 = 0; c4 < 32; ++c4) {
            const float4 h = hp4[c4];
            sum += (h.x + h.y) + (h.z + h.w);
            s2  += h.x * h.x + h.y * h.y + h.z * h.z + h.w * h.w;
            const int c = 4 * c4;
            sub0 += h.x * swl[2 * c] + h.y * swl[2 * c + 2] + h.z * swl[2 * c + 4] + h.w * swl[2 * c + 6];
            sub1 += h.x * swl[2 * c + 1] + h.y * swl[2 * c + 3] + h.z * swl[2 * c + 5] + h.w * swl[2 * c + 7];
        }
        const float u = sum * (1.f / 128.f);
        const float v = fmaxf(s2 * (1.f / 128.f) - u * u, 0.f);
        urs[s][0] = u;
        urs[s][1] = 1.f / sqrtf(v + 1e-12f);
        subv[2 * s] = sub0; subv[2 * s + 1] = sub1;
    }
    __syncthreads();

    // po head per (slot, o)
    for (int i = T; i < nslot * 20; i += 256) {
        const int s = i / 20, o = i - 20 * s;
        const float u = urs[s][0], rs = urs[s][1];
        const float4* hp4 = (const float4*)(hbuf + ((size_t)b * SLOTS + s) * 128);
        const float* Ao = &A[o][0];
        float acc = 0.f;
        for (int c4 = 0; c4 < 32; ++c4) {
            const float4 h = hp4[c4];
            const float4 aa = *(const float4*)&Ao[4 * c4];
            acc += h.x * aa.x + h.y * aa.y + h.z * aa.z + h.w * aa.w;
        }
        povals[i] = rs * acc - u * rs * K2[o] + K1[o];
    }
    __syncthreads();

    // scatter
    for (int i = T; i < 2560; i += 256) {
        const int t = i / 5, j = i - 5 * t;
        const int sl = idxr[t];
        const float4 v = *(const float4*)&povals[sl * 20 + 4 * j];
        *(float4*)&out[262144 + ((size_t)(b * 512 + t)) * 20 + 4 * j] = v;
    }
    for (int i = T; i < 512; i += 256) {
        const int sl = idxr[i];
        float2 v; v.x = subv[2 * sl]; v.y = subv[2 * sl + 1];
        *(float2*)&out[((size_t)(b * 512 + i)) * 2] = v;
    }
}

extern "C" void kernel_launch(void* const* d_in, const int* in_sizes, int n_in,
                              void* d_out, int out_size, void* d_ws, size_t ws_size,
                              hipStream_t stream) {
    (void)in_sizes; (void)n_in; (void)out_size; (void)ws_size;
    const int*   char_ids    = (const int*)d_in[0];
    const int*   word_ids    = (const int*)d_in[1];
    const int*   subject_ids = (const int*)d_in[2];
    const float* emb_char    = (const float*)d_in[3];
    const float* emb_word    = (const float*)d_in[4];
    const float* Wwc         = (const float*)d_in[5];
    const float* bwc         = (const float*)d_in[6];
    const float* l1_Wx       = (const float*)d_in[7];
    const float* l1_Wh       = (const float*)d_in[8];
    const float* l1_b        = (const float*)d_in[9];
    const float* l2_Wx       = (const float*)d_in[10];
    const float* l2_Wh       = (const float*)d_in[11];
    const float* l2_b        = (const float*)d_in[12];
    const float* beta_W      = (const float*)d_in[13];
    const float* beta_b      = (const float*)d_in[14];
    const float* gamma_W     = (const float*)d_in[15];
    const float* gamma_b     = (const float*)d_in[16];
    const float* sub_W       = (const float*)d_in[17];
    const float* sub_b       = (const float*)d_in[18];
    const float* po_W        = (const float*)d_in[19];
    const float* po_b        = (const float*)d_in[20];
    float* out = (float*)d_out;

    char* ws = (char*)d_ws;
    float*          XW1    = (float*)(ws + 0);               // 20480 B (pad 32768)
    uint4*          W1P    = (uint4*)(ws + 32768);           // 131072 B
    uint4*          W2P    = (uint4*)(ws + 163840);          // 262144 B
    unsigned short* idxbuf = (unsigned short*)(ws + 425984); // 262144 B
    float*          hbuf   = (float*)(ws + 688128);          // 25165824 B

    k_prep<<<dim3(106), dim3(256), 0, stream>>>(emb_char, emb_word, Wwc, bwc,
                                                l1_Wx, l1_b, l1_Wh, l2_Wx, l2_Wh,
                                                XW1, W1P, W2P);
    k_lstm<<<dim3(256), dim3(256), 0, stream>>>(char_ids, word_ids, XW1, W1P, W2P,
                                                l2_b, hbuf, idxbuf);
    k_out<<<dim3(256), dim3(256), 0, stream>>>(subject_ids, idxbuf, hbuf,
                                               beta_W, beta_b, gamma_W, gamma_b,
                                               sub_W, sub_b, po_W, po_b, out);
}

// Round 4
// 343.850 us; speedup vs baseline: 1.7940x; 1.7940x over previous
//
#include <hip/hip_runtime.h>
#include <cstdint>
#include <cstddef>

// PointerNetwork: B=256, S=512, H=128, CHAR/CLASS=10, OUT=64, WE=32
// R3 design: MFMA row-batched lockstep recurrence.
//  - k_front: per-row active-step scan (idx map, word list, nact) + XW1 table
//  - k_pack:  weights -> f16 MFMA B-fragments (l1_Wh + XW1 one-hot ext; l2_Wx; l2_Wh)
//  - k_A: layer-1 LSTM, 16 rows/block, 8 waves; wave owns 16 units x 4 gates
//         (nt = {w,w+8,w+16,w+24}); gates in registers; 1 barrier/step;
//         h1 state double-buffered in LDS (A-frag layout); h1 seq -> global.
//  - k_C: layer-2; resident Wx+Wh frags (128 VGPR); h1 frags from L2; hbuf out.
//  - k_out: subject GEMV + per-slot LN/po/sub folded + scatter (R2, SLOTCAP=128)

#define SLOTCAP 128
#define WSTR 130          // wtile LDS stride in u16 (conflict break)

typedef _Float16 half8 __attribute__((ext_vector_type(8)));
typedef float floatx4 __attribute__((ext_vector_type(4)));

union Frag { uint4 u; half8 h; };

__device__ __forceinline__ float fast_rcp(float x) {
#if __has_builtin(__builtin_amdgcn_rcpf)
    return __builtin_amdgcn_rcpf(x);
#else
    return 1.f / x;
#endif
}
__device__ __forceinline__ float sigm(float x) {
    x = fminf(fmaxf(x, -30.f), 30.f);
    return fast_rcp(1.f + __expf(-x));
}
__device__ __forceinline__ float tanh_fast(float x) {
    x = fminf(fmaxf(x, -15.f), 15.f);
    float e = __expf(-2.f * x);
    return (1.f - e) * fast_rcp(1.f + e);
}

// ---------------- k_front: scan rows (blocks 0..255) + XW1 (blocks 256..265) -
__global__ __launch_bounds__(256) void k_front(
    const int* __restrict__ char_ids, const int* __restrict__ word_ids,
    const float* __restrict__ emb_char, const float* __restrict__ emb_word,
    const float* __restrict__ Wwc, const float* __restrict__ bwc,
    const float* __restrict__ l1_Wx, const float* __restrict__ l1_b,
    float* __restrict__ XW1, unsigned short* __restrict__ idxbuf,
    unsigned short* __restrict__ wlist, int* __restrict__ nactG)
{
    const int T = threadIdx.x;
    __shared__ int charL[512];
    __shared__ int wordL[512];
    __shared__ short actT[512];
    __shared__ int ccnt[8];
    __shared__ float xt[64];

    if (blockIdx.x >= 256) {
        // ---- XW1 role: word w = blockIdx-256 ----
        const int w = blockIdx.x - 256;
        if (T < 64) {
            float acc = emb_char[T] + bwc[T];   // emb_char row 0 (char_id==0)
            for (int m = 0; m < 32; ++m) acc += emb_word[w * 32 + m] * Wwc[m * 64 + T];
            xt[T] = acc;
        }
        __syncthreads();
        for (int col = T; col < 512; col += 256) {
            float acc = l1_b[col];
            for (int k = 0; k < 64; ++k) acc += xt[k] * l1_Wx[k * 512 + col];
            XW1[w * 512 + col] = acc;
        }
        return;
    }

    // ---- scan role: row b ----
    const int b = blockIdx.x;
    const int lane = T & 63;
    const int wv = T >> 6;   // 0..3
    charL[T] = char_ids[b * 512 + T];
    charL[256 + T] = char_ids[b * 512 + 256 + T];
    wordL[T] = word_ids[b * 512 + T];
    wordL[256 + T] = word_ids[b * 512 + 256 + T];
    __syncthreads();

    const bool a0 = (charL[T] == 0);
    const bool a1 = (charL[256 + T] == 0);
    const unsigned long long m0 = __ballot(a0);
    const unsigned long long m1 = __ballot(a1);
    if (lane == 0) { ccnt[wv] = (int)__popcll(m0); ccnt[4 + wv] = (int)__popcll(m1); }
    __syncthreads();
    int base0 = 0, base4 = 0, tot = 0;
    for (int i = 0; i < 8; ++i) {
        const int c = ccnt[i];
        if (i < wv) base0 += c;
        if (i < 4 + wv) base4 += c;
        tot += c;
    }
    const unsigned long long below = (1ull << lane) - 1ull;
    const unsigned long long upto  = (2ull << lane) - 1ull;
    if (a0) actT[base0 + (int)__popcll(m0 & below)] = (short)T;
    if (a1) actT[base4 + (int)__popcll(m1 & below)] = (short)(256 + T);
    {
        int c0 = base0 + (int)__popcll(m0 & upto);
        int c1 = base4 + (int)__popcll(m1 & upto);
        idxbuf[b * 512 + T] = (unsigned short)(c0 < SLOTCAP - 1 ? c0 : SLOTCAP - 1);
        idxbuf[b * 512 + 256 + T] = (unsigned short)(c1 < SLOTCAP - 1 ? c1 : SLOTCAP - 1);
    }
    __syncthreads();
    const int nclamp = (tot < SLOTCAP - 1) ? tot : SLOTCAP - 1;
    for (int a2 = T; a2 < nclamp; a2 += 256)
        wlist[b * SLOTCAP + a2] = (unsigned short)wordL[actT[a2]];
    if (T == 0) nactG[b] = nclamp;
}

// ---------------- k_pack: weights -> f16 B-fragments -------------------------
// B-frag element: lane l: col = colbase + (l&15), k = 32*kt + 8*(l>>4) + j.
// BA: [w][g*5+kt][lane], kt=4 is the XW1 one-hot extension (rows = XW1 table).
// BX/BH: [w][g*4+kt][lane] from l2_Wx / l2_Wh.
__global__ __launch_bounds__(256) void k_pack(
    const float* __restrict__ l1_Wh, const float* __restrict__ l2_Wx,
    const float* __restrict__ l2_Wh, const float* __restrict__ XW1,
    uint4* __restrict__ BA, uint4* __restrict__ BX, uint4* __restrict__ BH)
{
    const int gid = blockIdx.x * blockDim.x + threadIdx.x;  // 26624 total
    const int fid = gid >> 6;       // 0..415
    const int lane = gid & 63;
    const int q = lane >> 4, lm = lane & 15;
    Frag out;
    if (fid < 160) {
        const int w = fid / 20, rem = fid - 20 * w;
        const int g = rem / 5, kt = rem - 5 * g;
        const int col = 128 * g + 16 * w + lm;
        if (kt < 4) {
            for (int j = 0; j < 8; ++j)
                out.h[j] = (_Float16)l1_Wh[(32 * kt + 8 * q + j) * 512 + col];
        } else {
            for (int j = 0; j < 8; ++j) {
                const int kp = 8 * q + j;
                out.h[j] = (kp < 10) ? (_Float16)XW1[kp * 512 + col] : (_Float16)0.f;
            }
        }
        BA[fid * 64 + lane] = out.u;
    } else if (fid < 288) {
        const int f2 = fid - 160;
        const int w = f2 >> 4, rem = f2 & 15;
        const int g = rem >> 2, kt = rem & 3;
        const int col = 128 * g + 16 * w + lm;
        for (int j = 0; j < 8; ++j)
            out.h[j] = (_Float16)l2_Wx[(32 * kt + 8 * q + j) * 512 + col];
        BX[f2 * 64 + lane] = out.u;
    } else {
        const int f3 = fid - 288;
        const int w = f3 >> 4, rem = f3 & 15;
        const int g = rem >> 2, kt = rem & 3;
        const int col = 128 * g + 16 * w + lm;
        for (int j = 0; j < 8; ++j)
            out.h[j] = (_Float16)l2_Wh[(32 * kt + 8 * q + j) * 512 + col];
        BH[f3 * 64 + lane] = out.u;
    }
}

// ---------------- k_A: layer-1 recurrence, 16 rows/block ---------------------
__global__ __launch_bounds__(512) void k_A(
    const uint4* __restrict__ BA, const unsigned short* __restrict__ wlist,
    const int* __restrict__ nactG, _Float16* __restrict__ h1s)
{
    const int r = blockIdx.x;       // row tile: rows 16r..16r+15
    const int T = threadIdx.x;
    const int w = T >> 6, l = T & 63;
    const int lq = l >> 4, lm = l & 15;

    __shared__ uint4 h1L[2][256];               // double-buffered h1, A-frag layout
    __shared__ unsigned short wt[16 * WSTR];
    __shared__ int nmax_s;

    // resident B-fragments (20 x 4 = 80 VGPR)
    Frag wf[20];
    {
        const uint4* p = BA + (size_t)(w * 20) * 64 + l;
#pragma unroll
        for (int i = 0; i < 20; ++i) wf[i].u = p[i * 64];
    }
    for (int i = T; i < 16 * SLOTCAP; i += 512) {
        const int m = i >> 7, a = i & (SLOTCAP - 1);
        wt[m * WSTR + a] = wlist[(16 * r + m) * SLOTCAP + a];
    }
    if (T < 256) h1L[0][T] = make_uint4(0, 0, 0, 0);
    int nact4[4];
#pragma unroll
    for (int rr = 0; rr < 4; ++rr) nact4[rr] = nactG[16 * r + 4 * lq + rr];
    if (T == 0) {
        int mx = 0;
        for (int m = 0; m < 16; ++m) { const int v = nactG[16 * r + m]; mx = v > mx ? v : mx; }
        nmax_s = mx;
    }
    __syncthreads();
    const int nmax = nmax_s;

    // h1s write coords (lane-uniform parts)
    const int kt_w = w >> 1;
    const int qq = (2 * w + (lm >> 3)) & 3;
    const int jm = lm & 7;
    const int u = 16 * w + lm;   (void)u;

    float c1[4] = {0.f, 0.f, 0.f, 0.f};
    float hreg[4] = {0.f, 0.f, 0.f, 0.f};

    for (int a = 0; a < nmax; ++a) {
        const int cur = a & 1, nxt = cur ^ 1;
        Frag ha[5];
#pragma unroll
        for (int kt = 0; kt < 4; ++kt) ha[kt].u = h1L[cur][kt * 64 + l];
        {   // one-hot XW1 extension frag (row lm's word at step a)
            const int wm = wt[lm * WSTR + a];
            half8 e;
#pragma unroll
            for (int j = 0; j < 8; ++j)
                e[j] = (8 * lq + j == wm) ? (_Float16)1.f : (_Float16)0.f;
            ha[4].h = e;
        }
        floatx4 acc[4];
#pragma unroll
        for (int g = 0; g < 4; ++g) {
            floatx4 z = {0.f, 0.f, 0.f, 0.f};
#pragma unroll
            for (int kt = 0; kt < 5; ++kt)
                z = __builtin_amdgcn_mfma_f32_16x16x32_f16(ha[kt].h, wf[g * 5 + kt].h, z, 0, 0, 0);
            acc[g] = z;
        }
        _Float16* nb = (_Float16*)&h1L[nxt][0];
#pragma unroll
        for (int rr = 0; rr < 4; ++rr) {
            const float zi = acc[0][rr], zf = acc[1][rr], zg = acc[2][rr], zo = acc[3][rr];
            const float si = sigm(zi), sf = sigm(zf);
            const float tg = tanh_fast(zg), so = sigm(zo);
            const float cn = sf * c1[rr] + si * tg;
            const float hn = so * tanh_fast(cn);
            const bool act = (a < nact4[rr]);
            c1[rr] = act ? cn : c1[rr];
            hreg[rr] = act ? hn : hreg[rr];
            const int lanew = qq * 16 + 4 * lq + rr;
            const _Float16 hv = (_Float16)hreg[rr];
            nb[(kt_w * 64 + lanew) * 8 + jm] = hv;
            if (act)
                h1s[(((size_t)(r * SLOTCAP + a) * 4 + kt_w) * 64 + lanew) * 8 + jm] = hv;
        }
        __syncthreads();
    }
}

// ---------------- k_C: layer-2 recurrence ------------------------------------
__global__ __launch_bounds__(512) void k_C(
    const uint4* __restrict__ BX, const uint4* __restrict__ BH,
    const _Float16* __restrict__ h1s, const float* __restrict__ l2_b,
    const int* __restrict__ nactG, float* __restrict__ hbuf)
{
    const int r = blockIdx.x;
    const int T = threadIdx.x;
    const int w = T >> 6, l = T & 63;
    const int lq = l >> 4, lm = l & 15;

    __shared__ uint4 h2L[2][256];
    __shared__ int nmax_s;

    Frag wx[16], wh[16];
    {
        const uint4* px = BX + (size_t)(w * 16) * 64 + l;
        const uint4* ph = BH + (size_t)(w * 16) * 64 + l;
#pragma unroll
        for (int i = 0; i < 16; ++i) { wx[i].u = px[i * 64]; wh[i].u = ph[i * 64]; }
    }
    float bias4[4];
#pragma unroll
    for (int g = 0; g < 4; ++g) bias4[g] = l2_b[128 * g + 16 * w + lm];
    if (T < 256) h2L[0][T] = make_uint4(0, 0, 0, 0);
    // hbuf slot 0 = zeros for this block's 16 rows
    for (int i = T; i < 2048; i += 512)
        hbuf[((size_t)(16 * r + (i >> 7)) * SLOTCAP) * 128 + (i & 127)] = 0.f;
    int nact4[4];
#pragma unroll
    for (int rr = 0; rr < 4; ++rr) nact4[rr] = nactG[16 * r + 4 * lq + rr];
    if (T == 0) {
        int mx = 0;
        for (int m = 0; m < 16; ++m) { const int v = nactG[16 * r + m]; mx = v > mx ? v : mx; }
        nmax_s = mx;
    }
    __syncthreads();
    const int nmax = nmax_s;

    const int kt_w = w >> 1;
    const int qq = (2 * w + (lm >> 3)) & 3;
    const int jm = lm & 7;
    const int u = 16 * w + lm;

    float c2[4] = {0.f, 0.f, 0.f, 0.f};
    float hreg[4] = {0.f, 0.f, 0.f, 0.f};

    for (int a = 0; a < nmax; ++a) {
        const int cur = a & 1, nxt = cur ^ 1;
        // h1 A-frags from global (L2-resident slice), issued first
        Frag hx[4];
        {
            const uint4* hp = (const uint4*)h1s + (size_t)(r * SLOTCAP + a) * 4 * 64 + l;
#pragma unroll
            for (int kt = 0; kt < 4; ++kt) hx[kt].u = hp[kt * 64];
        }
        Frag h2f[4];
#pragma unroll
        for (int kt = 0; kt < 4; ++kt) h2f[kt].u = h2L[cur][kt * 64 + l];
        floatx4 acc[4];
#pragma unroll
        for (int g = 0; g < 4; ++g) {
            floatx4 z = {bias4[g], bias4[g], bias4[g], bias4[g]};
#pragma unroll
            for (int kt = 0; kt < 4; ++kt)
                z = __builtin_amdgcn_mfma_f32_16x16x32_f16(h2f[kt].h, wh[g * 4 + kt].h, z, 0, 0, 0);
#pragma unroll
            for (int kt = 0; kt < 4; ++kt)
                z = __builtin_amdgcn_mfma_f32_16x16x32_f16(hx[kt].h, wx[g * 4 + kt].h, z, 0, 0, 0);
            acc[g] = z;
        }
        _Float16* nb = (_Float16*)&h2L[nxt][0];
#pragma unroll
        for (int rr = 0; rr < 4; ++rr) {
            const float zi = acc[0][rr], zf = acc[1][rr], zg = acc[2][rr], zo = acc[3][rr];
            const float si = sigm(zi), sf = sigm(zf);
            const float tg = tanh_fast(zg), so = sigm(zo);
            const float cn = sf * c2[rr] + si * tg;
            const float hn = so * tanh_fast(cn);
            const bool act = (a < nact4[rr]);
            c2[rr] = act ? cn : c2[rr];
            hreg[rr] = act ? hn : hreg[rr];
            const int m2 = 4 * lq + rr;
            const int lanew = qq * 16 + m2;
            nb[(kt_w * 64 + lanew) * 8 + jm] = (_Float16)hreg[rr];
            if (act)
                hbuf[((size_t)(16 * r + m2) * SLOTCAP + (a + 1)) * 128 + u] = hreg[rr];
        }
        __syncthreads();
    }
}

// ---------------- k_out: subject GEMV + per-slot LN/po/sub + scatter ---------
__global__ __launch_bounds__(256) void k_out(
    const int* __restrict__ subject_ids,
    const unsigned short* __restrict__ idxbuf, const float* __restrict__ hbuf,
    const float* __restrict__ beta_W, const float* __restrict__ beta_b,
    const float* __restrict__ gamma_W, const float* __restrict__ gamma_b,
    const float* __restrict__ sub_W, const float* __restrict__ sub_b,
    const float* __restrict__ po_W, const float* __restrict__ po_b,
    float* __restrict__ out)
{
    const int b = blockIdx.x;
    const int T = threadIdx.x;   // 0..255
    __shared__ float A[20][132];          // A[o][c] = gm[c]*po_W[c*20+o]
    __shared__ float K1[20], K2[20];
    __shared__ float gm[128], bt[128];
    __shared__ float subj[256];
    __shared__ float urs[SLOTCAP][2];
    __shared__ float povals[SLOTCAP * 20];
    __shared__ float subv[SLOTCAP * 2];
    __shared__ unsigned short idxr[512];
    __shared__ float swl[256];

    idxr[T] = idxbuf[b * 512 + T];
    idxr[256 + T] = idxbuf[b * 512 + 256 + T];
    swl[T] = sub_W[T];
    {
        const int s0 = subject_ids[b * 2 + 0];
        const int s1 = subject_ids[b * 2 + 1];
        const int i0 = idxbuf[b * 512 + s0];
        const int i1 = idxbuf[b * 512 + s1];
        if (T < 128) subj[T] = hbuf[((size_t)b * SLOTCAP + i0) * 128 + T];
        else         subj[T] = hbuf[((size_t)b * SLOTCAP + i1) * 128 + (T - 128)];
    }
    __syncthreads();

    {   // beta (T<128) / gamma (T>=128) GEMV
        const int uu = T & 127;
        const float* Wm = (T < 128) ? beta_W : gamma_W;
        float acc = (T < 128) ? beta_b[uu] : gamma_b[uu];
        for (int c = 0; c < 256; ++c) acc += subj[c] * Wm[c * 128 + uu];
        if (T < 128) bt[uu] = acc; else gm[uu] = acc;
    }
    __syncthreads();

    for (int i = T; i < 2560; i += 256) {
        const int o = i >> 7, c = i & 127;
        A[o][c] = gm[c] * po_W[c * 20 + o];
    }
    if (T < 20) {
        float k1 = po_b[T], k2 = 0.f;
        for (int c = 0; c < 128; ++c) {
            const float pw = po_W[c * 20 + T];
            k1 += bt[c] * pw;
            k2 += gm[c] * pw;
        }
        K1[T] = k1; K2[T] = k2;
    }
    const int nslot = (int)idxr[511] + 1;
    const float sb0 = sub_b[0], sb1 = sub_b[1];
    for (int s = T; s < nslot; s += 256) {
        const float4* hp4 = (const float4*)(hbuf + ((size_t)b * SLOTCAP + s) * 128);
        float sum = 0.f, s2 = 0.f, sub0 = sb0, sub1 = sb1;
        for (int c4 = 0; c4 < 32; ++c4) {
            const float4 h = hp4[c4];
            sum += (h.x + h.y) + (h.z + h.w);
            s2  += h.x * h.x + h.y * h.y + h.z * h.z + h.w * h.w;
            const int c = 4 * c4;
            sub0 += h.x * swl[2 * c] + h.y * swl[2 * c + 2] + h.z * swl[2 * c + 4] + h.w * swl[2 * c + 6];
            sub1 += h.x * swl[2 * c + 1] + h.y * swl[2 * c + 3] + h.z * swl[2 * c + 5] + h.w * swl[2 * c + 7];
        }
        const float uu = sum * (1.f / 128.f);
        const float v = fmaxf(s2 * (1.f / 128.f) - uu * uu, 0.f);
        urs[s][0] = uu;
        urs[s][1] = 1.f / sqrtf(v + 1e-12f);
        subv[2 * s] = sub0; subv[2 * s + 1] = sub1;
    }
    __syncthreads();

    for (int i = T; i < nslot * 20; i += 256) {
        const int s = i / 20, o = i - 20 * s;
        const float uu = urs[s][0], rs = urs[s][1];
        const float4* hp4 = (const float4*)(hbuf + ((size_t)b * SLOTCAP + s) * 128);
        const float* Ao = &A[o][0];
        float acc = 0.f;
        for (int c4 = 0; c4 < 32; ++c4) {
            const float4 h = hp4[c4];
            const float4 aa = *(const float4*)&Ao[4 * c4];
            acc += h.x * aa.x + h.y * aa.y + h.z * aa.z + h.w * aa.w;
        }
        povals[i] = rs * acc - uu * rs * K2[o] + K1[o];
    }
    __syncthreads();

    for (int i = T; i < 2560; i += 256) {
        const int t = i / 5, j = i - 5 * t;
        const int sl = idxr[t];
        const float4 v = *(const float4*)&povals[sl * 20 + 4 * j];
        *(float4*)&out[262144 + ((size_t)(b * 512 + t)) * 20 + 4 * j] = v;
    }
    for (int i = T; i < 512; i += 256) {
        const int sl = idxr[i];
        float2 v; v.x = subv[2 * sl]; v.y = subv[2 * sl + 1];
        *(float2*)&out[((size_t)(b * 512 + i)) * 2] = v;
    }
}

extern "C" void kernel_launch(void* const* d_in, const int* in_sizes, int n_in,
                              void* d_out, int out_size, void* d_ws, size_t ws_size,
                              hipStream_t stream) {
    (void)in_sizes; (void)n_in; (void)out_size; (void)ws_size;
    const int*   char_ids    = (const int*)d_in[0];
    const int*   word_ids    = (const int*)d_in[1];
    const int*   subject_ids = (const int*)d_in[2];
    const float* emb_char    = (const float*)d_in[3];
    const float* emb_word    = (const float*)d_in[4];
    const float* Wwc         = (const float*)d_in[5];
    const float* bwc         = (const float*)d_in[6];
    const float* l1_Wx       = (const float*)d_in[7];
    const float* l1_Wh       = (const float*)d_in[8];
    const float* l1_b        = (const float*)d_in[9];
    const float* l2_Wx       = (const float*)d_in[10];
    const float* l2_Wh       = (const float*)d_in[11];
    const float* l2_b        = (const float*)d_in[12];
    const float* beta_W      = (const float*)d_in[13];
    const float* beta_b      = (const float*)d_in[14];
    const float* gamma_W     = (const float*)d_in[15];
    const float* gamma_b     = (const float*)d_in[16];
    const float* sub_W       = (const float*)d_in[17];
    const float* sub_b       = (const float*)d_in[18];
    const float* po_W        = (const float*)d_in[19];
    const float* po_b        = (const float*)d_in[20];
    float* out = (float*)d_out;

    char* ws = (char*)d_ws;
    float*          XW1    = (float*)(ws + 0);                // 20480 B
    uint4*          BA     = (uint4*)(ws + 32768);            // 163840 B
    uint4*          BX     = (uint4*)(ws + 196608);           // 131072 B
    uint4*          BH     = (uint4*)(ws + 327680);           // 131072 B
    unsigned short* idxbuf = (unsigned short*)(ws + 458752);  // 262144 B
    unsigned short* wlist  = (unsigned short*)(ws + 720896);  // 65536 B
    int*            nactG  = (int*)(ws + 786432);             // 1024 B
    _Float16*       h1s    = (_Float16*)(ws + 1048576);       // 8388608 B
    float*          hbuf   = (float*)(ws + 9437184);          // 16777216 B

    k_front<<<dim3(266), dim3(256), 0, stream>>>(char_ids, word_ids, emb_char, emb_word,
                                                 Wwc, bwc, l1_Wx, l1_b,
                                                 XW1, idxbuf, wlist, nactG);
    k_pack<<<dim3(104), dim3(256), 0, stream>>>(l1_Wh, l2_Wx, l2_Wh, XW1, BA, BX, BH);
    k_A<<<dim3(16), dim3(512), 0, stream>>>(BA, wlist, nactG, h1s);
    k_C<<<dim3(16), dim3(512), 0, stream>>>(BX, BH, h1s, l2_b, nactG, hbuf);
    k_out<<<dim3(256), dim3(256), 0, stream>>>(subject_ids, idxbuf, hbuf,
                                               beta_W, beta_b, gamma_W, gamma_b,
                                               sub_W, sub_b, po_W, po_b, out);
}